// Round 1
// 302.586 us; speedup vs baseline: 1.0942x; 1.0942x over previous
//
#include <hip/hip_runtime.h>
#include <hip/hip_bf16.h>
#include <cstdint>

// DifferentiableILP on MI355X (gfx950).
// A = softmax(rule_weights[:,0,:]); 3x: facts = max(facts, colmax(A @ facts)).
// Columns independent -> each block owns a 64-col stripe, bf16 MFMA 16x16x32.
//
// R3 changes vs R2 (331us total, ilp 180us, MfmaUtil 23.5%, latency-bound):
//  - facts-update folded into bF load: update is max with per-column scalar m(c),
//    m monotone -> ft stays immutable after stage; fold = packed u16 max
//    (nonneg bf16 compares as u16). Deletes the 64KB LDS RMW pass + 1 barrier/iter.
//  - gm global atomics replaced by 2KB double-buffered LDS cross-wave reduce;
//    running col-max lives in registers. No global scratch at all.
//  - bF double-buffered (prefetch kt+1 under the MFMA cluster); kt=15 wrap
//    prefetch feeds next iteration's aF[0], overlapping A L2 latency with reduce.
//  - s_setprio(1) around MFMA cluster (2 blocks/CU at different phases).
//  - stage/epilogue use float2 (2 cols/lane): half the global instructions.

typedef __attribute__((ext_vector_type(8))) short bf16x8;   // 8 bf16 = 4 VGPRs
typedef __attribute__((ext_vector_type(8))) unsigned short u16x8;
typedef __attribute__((ext_vector_type(4))) float f32x4;
typedef unsigned short ushort_t;
typedef unsigned int uint32;

#define PDIM 512
#define CDIM 65536
#define NT   64      // columns per block

__device__ __forceinline__ ushort_t f2bf(float x) {          // RNE float->bf16
    uint32 u = __float_as_uint(x);
    return (ushort_t)((u + 0x7fffu + ((u >> 16) & 1u)) >> 16);
}
__device__ __forceinline__ float bf2f(uint32 bits) { return __uint_as_float(bits << 16); }

// packed max(v, splat(mu)) in the u16 domain (valid: all values are nonneg bf16)
__device__ __forceinline__ bf16x8 pkmax8(bf16x8 v, ushort_t mu) {
    u16x8 a = __builtin_bit_cast(u16x8, v);
    const u16x8 mb = {mu, mu, mu, mu, mu, mu, mu, mu};
    a = __builtin_elementwise_max(a, mb);
    return __builtin_bit_cast(bf16x8, a);
}

// ---- phase 1: softmax row r, written directly in MFMA-fragment-linear layout:
// Apk 16B-chunk index idx16 = kt*2048 + rg*64 + (quad*16 + m)
//   holds A[rg*16 + m][kt*32 + quad*8 .. +7] as 8 bf16.
__global__ __launch_bounds__(64) void softmax_pack(const float* __restrict__ rw,
                                                   ushort_t* __restrict__ Apk) {
    const int r  = blockIdx.x;
    const int ln = threadIdx.x;
    const float* row = rw + r * PDIM;
    float4 x0 = *(const float4*)(row + ln * 8);
    float4 x1 = *(const float4*)(row + ln * 8 + 4);
    float v[8] = {x0.x, x0.y, x0.z, x0.w, x1.x, x1.y, x1.z, x1.w};

    float mx = -1e30f;
    #pragma unroll
    for (int i = 0; i < 8; ++i) mx = fmaxf(mx, v[i]);
    #pragma unroll
    for (int d = 1; d < 64; d <<= 1) mx = fmaxf(mx, __shfl_xor(mx, d, 64));
    float s = 0.f;
    #pragma unroll
    for (int i = 0; i < 8; ++i) { v[i] = __expf(v[i] - mx); s += v[i]; }
    #pragma unroll
    for (int d = 1; d < 64; d <<= 1) s += __shfl_xor(s, d, 64);
    const float inv = 1.f / s;

    ushort_t o[8];
    #pragma unroll
    for (int i = 0; i < 8; ++i) o[i] = f2bf(v[i] * inv);
    // this lane holds elements p = ln*8 .. +7  ->  kt = ln>>2, quad = ln&3
    const int idx16 = (ln >> 2) * 2048 + (r >> 4) * 64 + ((ln & 3) << 4) + (r & 15);
    *(int4*)(Apk + idx16 * 8) = *(const int4*)o;
}

// ---- phase 2: per-64-column stripe, fused multi-iteration fixpoint.
// LDS ft[c][p] bf16, 16B-granule XOR swizzle: logical granule g of row c at slot g^(c&7).
// ft is IMMUTABLE after stage; running column max folded into bF at load time.
__global__ __launch_bounds__(256, 2) void ilp_kernel(
        const float* __restrict__ facts,
        const ushort_t* __restrict__ Apk,
        const int* __restrict__ n_iter_p,
        float* __restrict__ out) {
    __shared__ ushort_t ft[NT * PDIM];     // 65536 B
    __shared__ float wred[2][4][NT];       // 2048 B: per-wave colmax partials, dbuf
    __shared__ float mfin[NT];             // 256 B: final column max for epilogue

    const int tid  = threadIdx.x;
    const int wave = tid >> 6;
    const int lane = tid & 63;
    const int l15  = lane & 15;
    const int quad = lane >> 4;
    const int c0   = blockIdx.x * NT;

    // ---- stage: ft[c][p] = bf16(facts[p][c0+c]); float2 -> 2 cols per lane
    {
        const int ch = (tid & 31) * 2;     // even col
        const int pb = tid >> 5;           // 0..7
        #pragma unroll 4
        for (int s = 0; s < 8; ++s) {
            const int p0 = s * 64 + pb * 8;
            ushort_t ga[8], gb[8];
            #pragma unroll
            for (int i = 0; i < 8; ++i) {
                const float2 v = *(const float2*)(facts + (p0 + i) * CDIM + c0 + ch);
                ga[i] = f2bf(v.x);
                gb[i] = f2bf(v.y);
            }
            const int g = p0 >> 3;
            *(int4*)(&ft[ch * PDIM + ((g ^ (ch & 7)) << 3)])             = *(const int4*)ga;
            *(int4*)(&ft[(ch + 1) * PDIM + ((g ^ ((ch + 1) & 7)) << 3)]) = *(const int4*)gb;
        }
    }
    __syncthreads();

    int n_iter = *n_iter_p;
    n_iter = n_iter < 0 ? 0 : (n_iter > 8 ? 8 : n_iter);

    // per-wave GEMM bases (32-bit element offsets)
    const int abase = wave * 4096 + lane * 8;        // + kt*16384 + rt*512
    int cbase[4], cx8[4];
    #pragma unroll
    for (int ct = 0; ct < 4; ++ct) {
        const int c = ct * 16 + l15;
        cbase[ct] = c * PDIM;
        cx8[ct]   = (c & 7) * 8;                     // element-scaled xor key
    }

    ushort_t ml[4] = {0, 0, 0, 0};                   // running colmax, bf16 bits
    float    mf[4] = {0.f, 0.f, 0.f, 0.f};          // running colmax, f32

    bf16x8 aF[2][8], bF[2][4];
    {   // aF kt=0 prefetch for it=0 (the kt=15 wrap sustains it thereafter)
        const ushort_t* ap = Apk + abase;
        #pragma unroll
        for (int rt = 0; rt < 8; ++rt) aF[0][rt] = *(const bf16x8*)(ap + rt * 512);
    }

    #pragma unroll 1
    for (int it = 0; it < n_iter; ++it) {
        f32x4 acc[8][4];
        #pragma unroll
        for (int rt = 0; rt < 8; ++rt)
            #pragma unroll
            for (int ct = 0; ct < 4; ++ct) acc[rt][ct] = (f32x4){0.f, 0.f, 0.f, 0.f};

        {   // bF kt=0 with fresh ml (kt=15 wrap used stale ml -> redo)
            const int g8 = quad * 8;
            #pragma unroll
            for (int ct = 0; ct < 4; ++ct)
                bF[0][ct] = pkmax8(*(const bf16x8*)(&ft[cbase[ct] + (g8 ^ cx8[ct])]), ml[ct]);
        }

        #pragma unroll 2
        for (int kt = 0; kt < 16; ++kt) {
            const int cur = kt & 1, nxt = cur ^ 1;
            const int ktn = (kt + 1) & 15;
            {   // prefetch next k-step's A (kt=15 wraps -> next iteration's kt=0)
                const ushort_t* ap = Apk + abase + ktn * 16384;
                #pragma unroll
                for (int rt = 0; rt < 8; ++rt) aF[nxt][rt] = *(const bf16x8*)(ap + rt * 512);
            }
            {   // prefetch next k-step's B, fold running colmax (u16 pk-max)
                const int g8 = (ktn * 4 + quad) * 8;
                #pragma unroll
                for (int ct = 0; ct < 4; ++ct)
                    bF[nxt][ct] = pkmax8(*(const bf16x8*)(&ft[cbase[ct] + (g8 ^ cx8[ct])]), ml[ct]);
            }
            __builtin_amdgcn_s_setprio(1);
            #pragma unroll
            for (int rt = 0; rt < 8; ++rt)
                #pragma unroll
                for (int ct = 0; ct < 4; ++ct)
                    acc[rt][ct] = __builtin_amdgcn_mfma_f32_16x16x32_bf16(
                        aF[cur][rt], bF[cur][ct], acc[rt][ct], 0, 0, 0);
            __builtin_amdgcn_s_setprio(0);
        }

        // ---- colmax fold (D: col=lane&15, row=quad*4+e), then cross-wave via LDS
        float mx[4];
        #pragma unroll
        for (int ct = 0; ct < 4; ++ct) {
            float m0 = -1e30f;
            #pragma unroll
            for (int rt = 0; rt < 8; ++rt)
                #pragma unroll
                for (int e = 0; e < 4; ++e) m0 = fmaxf(m0, acc[rt][ct][e]);
            m0 = fmaxf(m0, __shfl_xor(m0, 16, 64));
            m0 = fmaxf(m0, __shfl_xor(m0, 32, 64));
            mx[ct] = m0;
        }
        const int buf = it & 1;
        if (quad == 0) {
            #pragma unroll
            for (int ct = 0; ct < 4; ++ct) wred[buf][wave][ct * 16 + l15] = mx[ct];
        }
        __syncthreads();
        #pragma unroll
        for (int ct = 0; ct < 4; ++ct) {
            const int c = ct * 16 + l15;
            const float m = fmaxf(fmaxf(wred[buf][0][c], wred[buf][1][c]),
                                  fmaxf(wred[buf][2][c], wred[buf][3][c]));
            mf[ct] = fmaxf(mf[ct], m);    // monotone guard vs bf16 wobble
            ml[ct] = f2bf(mf[ct]);
        }
        // no second barrier: wred double-buffered; next write to this buf is
        // beyond the NEXT iteration's barrier, after all reads above.
    }

    // ---- publish final m per column for epilogue layout
    if (wave == 0 && quad == 0) {
        #pragma unroll
        for (int ct = 0; ct < 4; ++ct) mfin[ct * 16 + l15] = mf[ct];
    }
    __syncthreads();

    // ---- epilogue: out = max(ft, m_final); float2 stores, 2 cols per lane
    {
        const int ch = (tid & 31) * 2;
        const int pb = tid >> 5;
        const float ma = mfin[ch];
        const float mb = mfin[ch + 1];
        for (int s = 0; s < 8; ++s) {
            const int p0 = s * 64 + pb * 8;
            const int g = p0 >> 3;
            ushort_t ga[8], gb[8];
            *(int4*)ga = *(const int4*)(&ft[ch * PDIM + ((g ^ (ch & 7)) << 3)]);
            *(int4*)gb = *(const int4*)(&ft[(ch + 1) * PDIM + ((g ^ ((ch + 1) & 7)) << 3)]);
            #pragma unroll
            for (int i = 0; i < 8; ++i) {
                float2 v;
                v.x = fmaxf(bf2f(ga[i]), ma);
                v.y = fmaxf(bf2f(gb[i]), mb);
                *(float2*)(out + (p0 + i) * CDIM + c0 + ch) = v;
            }
        }
    }
}

extern "C" void kernel_launch(void* const* d_in, const int* in_sizes, int n_in,
                              void* d_out, int out_size, void* d_ws, size_t ws_size,
                              hipStream_t stream) {
    const float* facts    = (const float*)d_in[0];       // [512, 65536] fp32
    const float* rw       = (const float*)d_in[1];       // [512, 1, 512] fp32
    const int*   n_iter_p = (const int*)d_in[2];         // scalar 3
    float* out = (float*)d_out;

    ushort_t* Apk = (ushort_t*)d_ws;                     // 512 KB

    softmax_pack<<<PDIM, 64, 0, stream>>>(rw, Apk);
    ilp_kernel<<<CDIM / NT, 256, 0, stream>>>(facts, Apk, n_iter_p, out);
}